// Round 11
// baseline (56.876 us; speedup 1.0000x reference)
//
#include <hip/hip_runtime.h>
#include <hip/hip_bf16.h>
#include <math.h>

#define BN 8192
#define DK 128
#define NSPLIT 16
#define JR (BN / NSPLIT)    // 512 cols per split
#define NG (JR / 128)       // 4 intervals of 128 cols
#define MARGIN_F 1.0f
#define I32MIN (-2147483647 - 1)
#define I32MAX 2147483647

// ---------------- workspace layout (float-slot offsets from d_ws) -------------
// Eb  : bf16 8192x128 (B-side)            = 2MB
// EbS : bf16 8192x128 scaled by -128 (A)  = 2MB
// qt  : i32 [BN]  ((int)(64*sq_j) << 6) | target_j
// posP/negP: i32 [NSPLIT][BN] packed
// loss: f32 [BN]
#define OFF_EBS  524288
#define OFF_QT   1048576
#define OFF_POSP (OFF_QT + BN)
#define OFF_NEGP (OFF_POSP + NSPLIT * BN)
#define OFF_LOSS (OFF_NEGP + NSPLIT * BN)

typedef __attribute__((ext_vector_type(8))) short bf16x8;
typedef __attribute__((ext_vector_type(4))) float f32x4;

__device__ __forceinline__ unsigned short f2bf(float f) {
    __hip_bfloat16 h = __float2bfloat16(f);
    return *reinterpret_cast<unsigned short*>(&h);
}
__device__ __forceinline__ int imax(int a, int b) { return a > b ? a : b; }
__device__ __forceinline__ int imin(int a, int b) { return a < b ? a : b; }

__device__ __forceinline__ void gload_lds16(const void* g, void* s) {
    __builtin_amdgcn_global_load_lds(
        (const __attribute__((address_space(1))) void*)g,
        (__attribute__((address_space(3))) void*)s, 16, 0, 0);
}

// ---------------- prep: bf16 tables + packed (int(64*sq)<<6 | tgt) ------------
__global__ __launch_bounds__(256) void k_prep(const float* __restrict__ emb,
                                              const int* __restrict__ tgt,
                                              unsigned short* __restrict__ Eb,
                                              unsigned short* __restrict__ EbS,
                                              int* __restrict__ qt) {
    int row  = blockIdx.x * 4 + (threadIdx.x >> 6);
    int lane = threadIdx.x & 63;
    float2 v = ((const float2*)(emb + (size_t)row * DK))[lane];
    ushort2 o;  o.x  = f2bf(v.x);           o.y  = f2bf(v.y);
    ushort2 os; os.x = f2bf(v.x * -128.0f); os.y = f2bf(v.y * -128.0f);
    ((ushort2*)(Eb  + (size_t)row * DK))[lane] = o;
    ((ushort2*)(EbS + (size_t)row * DK))[lane] = os;
    float s = v.x * v.x + v.y * v.y;
    #pragma unroll
    for (int m = 32; m; m >>= 1) s += __shfl_xor(s, m);
    if (lane == 0) qt[row] = (((int)(64.0f * s)) << 6) | tgt[row];
}

// ---------------- fused MFMA Gram + batch-hard mining -------------------------
// Block = 4 waves; wave w owns 64 i-rows (A[4][4] regs from -128-pre-scaled
// table). Block covers 256 rows x one 512-col split (NSPLIT=16 -> 512 blocks
// = 2 blocks/CU, 2 waves/SIMD from DIFFERENT blocks -> desynced barriers).
// B: 128-col intervals, double-buffered 2x32KB LDS via async global_load_lds
// (zero-VGPR prefetch), 4 barriers total. Each 16KB LDS B-read now feeds 64
// i-rows (2x the round-10 output/byte -> LDS pipe load halved).
// acc init = 0 (no load->MFMA dependency); key folded at pack time:
//   k = (int)acc + (qt[j]>>6);  acc = (-128 x_i)·x_j = 64*(-2 dot)
// Packed-i32 mining: pos=max(qq^0x1FFF), neg=min(qq), qq=(k<<13)|j; ties->low j.
__global__ __launch_bounds__(256, 2)
void k_mine7(const unsigned short* __restrict__ Eb,
             const unsigned short* __restrict__ EbS,
             const int* __restrict__ qt,
             int* __restrict__ posP, int* __restrict__ negP) {
    __shared__ __align__(16) char Blds[2][2][16384];   // [buf][half][16KB]

    const int tid = threadIdx.x;
    const int w   = tid >> 6;
    const int l   = tid & 63;
    const int lh  = l >> 4;
    const int tx  = l & 15;
    const int igroup = blockIdx.x >> 4;   // 0..31
    const int split  = blockIdx.x & 15;   // 0..15
    const int i0w = igroup * 256 + w * 64;
    const int jb  = split * JR;
    const char* EbB = (const char*)Eb;

    // A fragments (64 rows per wave) from the -128-scaled table
    bf16x8 A[4][4];
    #pragma unroll
    for (int mi = 0; mi < 4; ++mi) {
        const char* rp = (const char*)EbS + (size_t)(i0w + mi * 16 + tx) * 256 + lh * 16;
        #pragma unroll
        for (int ks = 0; ks < 4; ++ks)
            A[mi][ks] = *(const bf16x8*)(rp + ks * 64);
    }

    // packed i-targets (<64): byte v of tpk[mi] = tgt[i0w + mi*16 + lh*4 + v]
    int tpk[4];
    #pragma unroll
    for (int mi = 0; mi < 4; ++mi) {
        int4 q = *(const int4*)(qt + i0w + mi * 16 + lh * 4);
        tpk[mi] = (q.x & 63) | ((q.y & 63) << 8) | ((q.z & 63) << 16) | ((q.w & 63) << 24);
    }

    int pp[16], nn[16];
    #pragma unroll
    for (int r = 0; r < 16; ++r) { pp[r] = I32MIN; nn[r] = I32MAX; }

    // stage one 64-col subtile (16KB), source-preswizzled:
    // LDS[row][c] = Eb[j0+row][c ^ (row&7)], c = 16B chunk; dst linear.
    auto stage64 = [&](char* dst, int jcol0) {
        const char* S = EbB + (size_t)jcol0 * 256;
        #pragma unroll
        for (int q = 0; q < 4; ++q) {
            int f  = tid + 256 * q;           // 0..1023
            int gr = f >> 4;                  // subtile row 0..63
            int sc = (f & 15) ^ (gr & 7);     // swizzled source chunk
            gload_lds16(S + gr * 256 + sc * 16, dst + w * 1024 + q * 4096);
        }
    };

    stage64(Blds[0][0], jb);
    stage64(Blds[0][1], jb + 64);
    __syncthreads();

    for (int g = 0; g < NG; ++g) {
        const int buf = g & 1;
        if (g + 1 < NG) {                       // async prefetch next 128 cols
            stage64(Blds[buf ^ 1][0], jb + (g + 1) * 128);
            stage64(Blds[buf ^ 1][1], jb + (g + 1) * 128 + 64);
        }
        const int j0 = jb + g * 128;

        // per-interval column metadata (hoisted; hides under MFMA)
        int qv[4][2], jn_[4][2];
        #pragma unroll
        for (int s = 0; s < 4; ++s)
            #pragma unroll
            for (int u = 0; u < 2; ++u) {
                int j = j0 + s * 32 + u * 16 + tx;
                jn_[s][u] = j; qv[s][u] = qt[j];
            }

        #pragma unroll
        for (int s = 0; s < 4; ++s) {           // 32-col subtiles
            f32x4 acc[4][2];
            #pragma unroll
            for (int mi = 0; mi < 4; ++mi)
                #pragma unroll
                for (int u = 0; u < 2; ++u) {
                    f32x4 z = {0.f, 0.f, 0.f, 0.f};
                    acc[mi][u] = z;
                }

            const char* base = Blds[buf][s >> 1];
            #pragma unroll
            for (int ks = 0; ks < 4; ++ks) {
                bf16x8 Bf[2];
                #pragma unroll
                for (int u = 0; u < 2; ++u) {
                    int row = (s & 1) * 32 + u * 16 + tx;
                    int c   = (ks * 4 + lh) ^ (row & 7);
                    Bf[u] = *(const bf16x8*)(base + row * 256 + c * 16);
                }
                __builtin_amdgcn_s_setprio(1);
                #pragma unroll
                for (int mi = 0; mi < 4; ++mi)
                    #pragma unroll
                    for (int u = 0; u < 2; ++u)
                        acc[mi][u] = __builtin_amdgcn_mfma_f32_16x16x32_bf16(
                            A[mi][ks], Bf[u], acc[mi][u], 0, 0, 0);
                __builtin_amdgcn_s_setprio(0);
            }

            // mining epilogue: key = (int)acc + 64*sq_j(int) ; pack (k<<13)|j
            int iq0 = qv[s][0] >> 6, iq1 = qv[s][1] >> 6;
            int tj0 = qv[s][0] & 63, tj1 = qv[s][1] & 63;
            #pragma unroll
            for (int mi = 0; mi < 4; ++mi) {
                #pragma unroll
                for (int v = 0; v < 4; ++v) {
                    const int r   = mi * 4 + v;
                    const int trg = (tpk[mi] >> (8 * v)) & 0xFF;
                    int k0 = (int)acc[mi][0][v] + iq0;
                    int k1 = (int)acc[mi][1][v] + iq1;
                    int q0 = (int)(((unsigned)k0 << 13) | (unsigned)jn_[s][0]);
                    int q1 = (int)(((unsigned)k1 << 13) | (unsigned)jn_[s][1]);
                    bool s0 = (tj0 == trg);
                    bool s1 = (tj1 == trg);
                    pp[r] = imax(imax(pp[r], s0 ? (q0 ^ 0x1FFF) : I32MIN),
                                         s1 ? (q1 ^ 0x1FFF) : I32MIN);
                    nn[r] = imin(imin(nn[r], s0 ? I32MAX : q0), s1 ? I32MAX : q1);
                }
            }
        }

        __syncthreads();   // all waves done reading buf; prefetch complete
    }

    // reduce across the 16 tx lanes (packed compare: ties -> lowest j)
    #pragma unroll
    for (int r = 0; r < 16; ++r) {
        int p = pp[r], n = nn[r];
        #pragma unroll
        for (int m = 1; m < 16; m <<= 1) {
            p = imax(p, __shfl_xor(p, m));
            n = imin(n, __shfl_xor(n, m));
        }
        if (tx == 0) {
            int row = i0w + (r >> 2) * 16 + lh * 4 + (r & 3);
            posP[split * BN + row] = p;
            negP[split * BN + row] = n;
        }
    }
}

// ---------------- combine splits + exact f32 dp/dn + per-row loss -------------
__global__ __launch_bounds__(256) void k_fin(const float* __restrict__ emb,
                                             const int* __restrict__ posP,
                                             const int* __restrict__ negP,
                                             float* __restrict__ loss) {
    int row  = blockIdx.x * 4 + (threadIdx.x >> 6);
    int lane = threadIdx.x & 63;

    int p = I32MIN, n = I32MAX;
    if (lane < NSPLIT) {
        p = posP[lane * BN + row];
        n = negP[lane * BN + row];
    }
    #pragma unroll
    for (int m = 1; m < NSPLIT; m <<= 1) {
        p = imax(p, __shfl_xor(p, m));
        n = imin(n, __shfl_xor(n, m));
    }
    p = __shfl(p, 0); n = __shfl(n, 0);
    int bpi = 8191 - (p & 8191), bni = n & 8191;

    float2 a  = ((const float2*)(emb + (size_t)row * DK))[lane];
    float2 pv = ((const float2*)(emb + (size_t)bpi * DK))[lane];
    float2 nv = ((const float2*)(emb + (size_t)bni * DK))[lane];
    float dp = (a.x - pv.x) * (a.x - pv.x) + (a.y - pv.y) * (a.y - pv.y);
    float dn = (a.x - nv.x) * (a.x - nv.x) + (a.y - nv.y) * (a.y - nv.y);
    #pragma unroll
    for (int m = 32; m; m >>= 1) {
        dp += __shfl_xor(dp, m);
        dn += __shfl_xor(dn, m);
    }
    if (lane == 0) {
        float lo = sqrtf(dp) - sqrtf(dn) + MARGIN_F;
        loss[row] = lo > 0.f ? lo : 0.f;
    }
}

// ---------------- mean over BN losses ----------------
__global__ __launch_bounds__(256) void k_mean(const float* __restrict__ loss,
                                              float* __restrict__ out) {
    int tid = threadIdx.x;
    float s = 0.f;
    for (int q = tid; q < BN; q += 256) s += loss[q];
    #pragma unroll
    for (int m = 32; m; m >>= 1) s += __shfl_xor(s, m);
    __shared__ float wsum[4];
    if ((tid & 63) == 0) wsum[tid >> 6] = s;
    __syncthreads();
    if (tid == 0) out[0] = (wsum[0] + wsum[1] + wsum[2] + wsum[3]) * (1.0f / BN);
}

extern "C" void kernel_launch(void* const* d_in, const int* in_sizes, int n_in,
                              void* d_out, int out_size, void* d_ws, size_t ws_size,
                              hipStream_t stream) {
    const float* emb = (const float*)d_in[0];
    const int*   tgt = (const int*)d_in[1];
    float* out = (float*)d_out;

    float* wsf = (float*)d_ws;
    unsigned short* Eb  = (unsigned short*)wsf;
    unsigned short* EbS = (unsigned short*)(wsf + OFF_EBS);
    int*   qt   = (int*)(wsf + OFF_QT);
    int*   posP = (int*)(wsf + OFF_POSP);
    int*   negP = (int*)(wsf + OFF_NEGP);
    float* loss = wsf + OFF_LOSS;

    k_prep<<<BN / 4, 256, 0, stream>>>(emb, tgt, Eb, EbS, qt);
    k_mine7<<<(BN / 256) * NSPLIT, 256, 0, stream>>>(Eb, EbS, qt, posP, negP);
    k_fin<<<BN / 4, 256, 0, stream>>>(emb, posP, negP, loss);
    k_mean<<<1, 256, 0, stream>>>(loss, out);
}

// Round 12
// 44.838 us; speedup vs baseline: 1.2685x; 1.2685x over previous
//
#include <hip/hip_runtime.h>
#include <hip/hip_bf16.h>
#include <math.h>

#define BN 8192
#define DK 128
#define NSPLIT 16
#define JR (BN / NSPLIT)    // 512 cols per split
#define NG (JR / 128)       // 4 intervals of 128 cols
#define MARGIN_F 1.0f

// ---------------- workspace layout (float-slot offsets from d_ws) -------------
// Eb  : bf16 8192x128 (B-side)            = 2MB
// EbS : bf16 8192x128 scaled by -128 (A)  = 2MB
// sq64: f32 [BN]  64*sum(x^2)
// posV/negV: f32 [NSPLIT][BN] mined key values (64*(sq_j-2dot))
// red : ull sum + uint counter (16B)
#define OFF_EBS  524288
#define OFF_SQ   1048576
#define OFF_POSV (OFF_SQ + BN)
#define OFF_NEGV (OFF_POSV + NSPLIT * BN)
#define OFF_RED  (OFF_NEGV + NSPLIT * BN)

typedef __attribute__((ext_vector_type(8))) short bf16x8;
typedef __attribute__((ext_vector_type(4))) float f32x4;

__device__ __forceinline__ unsigned short f2bf(float f) {
    __hip_bfloat16 h = __float2bfloat16(f);
    return *reinterpret_cast<unsigned short*>(&h);
}

__device__ __forceinline__ void gload_lds16(const void* g, void* s) {
    __builtin_amdgcn_global_load_lds(
        (const __attribute__((address_space(1))) void*)g,
        (__attribute__((address_space(3))) void*)s, 16, 0, 0);
}

// ---------------- prep: bf16 tables (plain + -128-scaled) + 64*rowsq ----------
__global__ __launch_bounds__(256) void k_prep(const float* __restrict__ emb,
                                              unsigned short* __restrict__ Eb,
                                              unsigned short* __restrict__ EbS,
                                              float* __restrict__ sq64) {
    int row  = blockIdx.x * 4 + (threadIdx.x >> 6);
    int lane = threadIdx.x & 63;
    float2 v = ((const float2*)(emb + (size_t)row * DK))[lane];
    ushort2 o;  o.x  = f2bf(v.x);           o.y  = f2bf(v.y);
    ushort2 os; os.x = f2bf(v.x * -128.0f); os.y = f2bf(v.y * -128.0f);
    ((ushort2*)(Eb  + (size_t)row * DK))[lane] = o;
    ((ushort2*)(EbS + (size_t)row * DK))[lane] = os;
    float s = v.x * v.x + v.y * v.y;
    #pragma unroll
    for (int m = 32; m; m >>= 1) s += __shfl_xor(s, m);
    if (lane == 0) sq64[row] = 64.0f * s;
}

// ---------------- fused MFMA Gram + batch-hard VALUE mining -------------------
// Geometry = round-11 (proven): 512 blocks = 32 igroups x 16 splits; block =
// 4 waves x 64 i-rows covering 256 rows x 512 cols; B in 128-col intervals,
// double-buffered 2x32KB LDS via async global_load_lds; 4 barriers.
// NEW: mine the f32 KEY VALUE only (no indices). acc init = 64*sq_j; MFMA adds
// (-128 x_i)·x_j  =>  acc = 64*(sq_j - 2 dot) = 64*key. Epilogue per element:
// cmp + cndmask(-INF/+INF) + v_max3/min3_f32 — half the int-path VALU.
// Self-pair: key_self = -64*sq_i << any real positive key -> never wins max.
__global__ __launch_bounds__(256)
void k_mine8(const unsigned short* __restrict__ Eb,
             const unsigned short* __restrict__ EbS,
             const float* __restrict__ sq64,
             const int* __restrict__ tgt,
             float* __restrict__ posV, float* __restrict__ negV) {
    __shared__ __align__(16) char Blds[2][2][16384];   // [buf][half][16KB]

    const int tid = threadIdx.x;
    const int w   = tid >> 6;
    const int l   = tid & 63;
    const int lh  = l >> 4;
    const int tx  = l & 15;
    const int igroup = blockIdx.x >> 4;   // 0..31
    const int split  = blockIdx.x & 15;   // 0..15
    const int i0w = igroup * 256 + w * 64;
    const int jb  = split * JR;
    const char* EbB = (const char*)Eb;

    // A fragments (64 rows per wave) from the -128-scaled table
    bf16x8 A[4][4];
    #pragma unroll
    for (int mi = 0; mi < 4; ++mi) {
        const char* rp = (const char*)EbS + (size_t)(i0w + mi * 16 + tx) * 256 + lh * 16;
        #pragma unroll
        for (int ks = 0; ks < 4; ++ks)
            A[mi][ks] = *(const bf16x8*)(rp + ks * 64);
    }

    // per-lane i-row targets: t8[mi*4+v] = tgt[i0w + mi*16 + lh*4 + v]
    int t8[16];
    #pragma unroll
    for (int mi = 0; mi < 4; ++mi) {
        int4 q = *(const int4*)(tgt + i0w + mi * 16 + lh * 4);
        t8[mi * 4 + 0] = q.x; t8[mi * 4 + 1] = q.y;
        t8[mi * 4 + 2] = q.z; t8[mi * 4 + 3] = q.w;
    }

    float pp[16], nn[16];
    #pragma unroll
    for (int r = 0; r < 16; ++r) { pp[r] = -INFINITY; nn[r] = INFINITY; }

    // stage one 64-col subtile (16KB), source-preswizzled:
    // LDS[row][c] = Eb[j0+row][c ^ (row&7)], c = 16B chunk; dst linear.
    auto stage64 = [&](char* dst, int jcol0) {
        const char* S = EbB + (size_t)jcol0 * 256;
        #pragma unroll
        for (int q = 0; q < 4; ++q) {
            int f  = tid + 256 * q;           // 0..1023
            int gr = f >> 4;                  // subtile row 0..63
            int sc = (f & 15) ^ (gr & 7);     // swizzled source chunk
            gload_lds16(S + gr * 256 + sc * 16, dst + w * 1024 + q * 4096);
        }
    };

    stage64(Blds[0][0], jb);
    stage64(Blds[0][1], jb + 64);
    __syncthreads();

    for (int g = 0; g < NG; ++g) {
        const int buf = g & 1;
        if (g + 1 < NG) {                       // async prefetch next 128 cols
            stage64(Blds[buf ^ 1][0], jb + (g + 1) * 128);
            stage64(Blds[buf ^ 1][1], jb + (g + 1) * 128 + 64);
        }
        const int j0 = jb + g * 128;

        // per-interval column metadata (hoisted; hides under MFMA)
        float sqv[4][2]; int tjv[4][2];
        #pragma unroll
        for (int s = 0; s < 4; ++s)
            #pragma unroll
            for (int u = 0; u < 2; ++u) {
                int j = j0 + s * 32 + u * 16 + tx;
                sqv[s][u] = sq64[j]; tjv[s][u] = tgt[j];
            }

        #pragma unroll
        for (int s = 0; s < 4; ++s) {           // 32-col subtiles
            f32x4 acc[4][2];
            #pragma unroll
            for (int mi = 0; mi < 4; ++mi)
                #pragma unroll
                for (int u = 0; u < 2; ++u) {
                    float sv = sqv[s][u];
                    f32x4 a0 = {sv, sv, sv, sv};
                    acc[mi][u] = a0;
                }

            const char* base = Blds[buf][s >> 1];
            #pragma unroll
            for (int ks = 0; ks < 4; ++ks) {
                bf16x8 Bf[2];
                #pragma unroll
                for (int u = 0; u < 2; ++u) {
                    int row = (s & 1) * 32 + u * 16 + tx;
                    int c   = (ks * 4 + lh) ^ (row & 7);
                    Bf[u] = *(const bf16x8*)(base + row * 256 + c * 16);
                }
                __builtin_amdgcn_s_setprio(1);
                #pragma unroll
                for (int mi = 0; mi < 4; ++mi)
                    #pragma unroll
                    for (int u = 0; u < 2; ++u)
                        acc[mi][u] = __builtin_amdgcn_mfma_f32_16x16x32_bf16(
                            A[mi][ks], Bf[u], acc[mi][u], 0, 0, 0);
                __builtin_amdgcn_s_setprio(0);
            }

            // value-mining epilogue: acc == 64*(sq_j - 2 dot) == 64*key
            const int tj0 = tjv[s][0], tj1 = tjv[s][1];
            #pragma unroll
            for (int mi = 0; mi < 4; ++mi) {
                #pragma unroll
                for (int v = 0; v < 4; ++v) {
                    const int r = mi * 4 + v;
                    const int trg = t8[r];
                    float k0 = acc[mi][0][v];
                    float k1 = acc[mi][1][v];
                    bool s0 = (tj0 == trg);
                    bool s1 = (tj1 == trg);
                    float a0 = s0 ? k0 : -INFINITY;
                    float b0 = s0 ? INFINITY : k0;
                    float a1 = s1 ? k1 : -INFINITY;
                    float b1 = s1 ? INFINITY : k1;
                    pp[r] = fmaxf(fmaxf(pp[r], a0), a1);   // -> v_max3_f32
                    nn[r] = fminf(fminf(nn[r], b0), b1);   // -> v_min3_f32
                }
            }
        }

        __syncthreads();   // all waves done reading buf; prefetch complete
    }

    // reduce across the 16 tx lanes
    #pragma unroll
    for (int r = 0; r < 16; ++r) {
        float p = pp[r], n = nn[r];
        #pragma unroll
        for (int m = 1; m < 16; m <<= 1) {
            p = fmaxf(p, __shfl_xor(p, m));
            n = fminf(n, __shfl_xor(n, m));
        }
        if (tx == 0) {
            int row = i0w + (r >> 2) * 16 + lh * 4 + (r & 3);
            posV[split * BN + row] = p;
            negV[split * BN + row] = n;
        }
    }
}

// ---------------- combine splits + loss + mean (fused, deterministic) ---------
// 32 blocks x 256 threads, 1 row/thread, streaming loads (no gathers).
// d2 = (key64 + 64*sq_i)/64, clamped >= 0 (matches ref's maximum(d2,0)).
// Block-sum f32 (fixed order) -> 2^-24 fixed-point -> 32 integer atomics
// (commutative-exact) -> last block writes the mean.
__global__ __launch_bounds__(256) void k_finm(const float* __restrict__ sq64,
                                              const float* __restrict__ posV,
                                              const float* __restrict__ negV,
                                              unsigned long long* __restrict__ red,
                                              float* __restrict__ out) {
    int row  = blockIdx.x * 256 + threadIdx.x;
    int lane = threadIdx.x & 63;

    float p = -INFINITY, n = INFINITY;
    #pragma unroll
    for (int s = 0; s < NSPLIT; ++s) {
        p = fmaxf(p, posV[s * BN + row]);
        n = fminf(n, negV[s * BN + row]);
    }
    float s64 = sq64[row];
    float d2p = fmaxf(p + s64, 0.f) * 0.015625f;
    float d2n = fmaxf(n + s64, 0.f) * 0.015625f;
    float lo  = sqrtf(d2p) - sqrtf(d2n) + MARGIN_F;
    lo = lo > 0.f ? lo : 0.f;

    #pragma unroll
    for (int m = 32; m; m >>= 1) lo += __shfl_xor(lo, m);
    __shared__ float part[4];
    if (lane == 0) part[threadIdx.x >> 6] = lo;
    __syncthreads();
    if (threadIdx.x == 0) {
        float bs = part[0] + part[1] + part[2] + part[3];
        atomicAdd(red, (unsigned long long)(bs * 16777216.0f));
        __threadfence();
        unsigned int t = atomicAdd((unsigned int*)(red + 1), 1u);
        if (t == gridDim.x - 1) {
            unsigned long long tot = atomicAdd(red, 0ULL);
            out[0] = (float)((double)tot / 16777216.0 / (double)BN);
        }
    }
}

extern "C" void kernel_launch(void* const* d_in, const int* in_sizes, int n_in,
                              void* d_out, int out_size, void* d_ws, size_t ws_size,
                              hipStream_t stream) {
    const float* emb = (const float*)d_in[0];
    const int*   tgt = (const int*)d_in[1];
    float* out = (float*)d_out;

    float* wsf = (float*)d_ws;
    unsigned short* Eb  = (unsigned short*)wsf;
    unsigned short* EbS = (unsigned short*)(wsf + OFF_EBS);
    float* sq64 = wsf + OFF_SQ;
    float* posV = wsf + OFF_POSV;
    float* negV = wsf + OFF_NEGV;
    unsigned long long* red = (unsigned long long*)(wsf + OFF_RED);

    hipMemsetAsync(red, 0, 16, stream);
    k_prep<<<BN / 4, 256, 0, stream>>>(emb, Eb, EbS, sq64);
    k_mine8<<<(BN / 256) * NSPLIT, 256, 0, stream>>>(Eb, EbS, sq64, tgt, posV, negV);
    k_finm<<<BN / 256, 256, 0, stream>>>(sq64, posV, negV, red, out);
}